// Round 3
// baseline (489.815 us; speedup 1.0000x reference)
//
#include <hip/hip_runtime.h>
#include <cmath>

// Workspace layout (in floats):
//   fq_all : 0       .. 245760   (256 x (64+128+256+512))
//   r2_all : 245760  .. 253760   (4 x 2000)
//   lid    : 253760  .. 254784   (256 x 4, [b][layer])
//   G_part : 262144  ..          (15 chunks x 256 x 2000)  ~31 MB total
#define WS_FQ_OFF      0u
#define WS_R2_OFF      245760u
#define WS_LID_OFF     253760u
#define WS_G_OFF       262144u
#define G_CHUNK_STRIDE 512000u
#define NREF           2000
#define KC             64       // split-K chunk width

// ---------------------------------------------------------------- pooling (fused, all layers)
// One wave per (b,c) row; compile-time HW -> fully unrolled, clustered loads.
template<int HW>
__device__ __forceinline__ void pool_row_vec(const float* __restrict__ feat,
                                             float* __restrict__ fq,
                                             int row, int lane) {
    constexpr int N4 = HW / 4;
    const float4* p4 = (const float4*)(feat + (size_t)row * HW);
    float s = 0.f;
    constexpr int ITER = (N4 + 63) / 64;
    #pragma unroll
    for (int it = 0; it < ITER; ++it) {
        int i = lane + it * 64;
        if ((N4 & 63) == 0 || i < N4) {
            float4 v = p4[i];
            s += (v.x + v.y) + (v.z + v.w);
        }
    }
    #pragma unroll
    for (int off = 32; off; off >>= 1) s += __shfl_down(s, off, 64);
    if (lane == 0) fq[row] = s * (1.0f / (float)HW);
}

__device__ __forceinline__ void pool_row_49(const float* __restrict__ feat,
                                            float* __restrict__ fq,
                                            int row, int lane) {
    const float* p = feat + (size_t)row * 49;
    float s = (lane < 49) ? p[lane] : 0.f;
    #pragma unroll
    for (int off = 32; off; off >>= 1) s += __shfl_down(s, off, 64);
    if (lane == 0) fq[row] = s * (1.0f / 49.0f);
}

// Block ranges: L0 [0,4096) L1 [4096,12288) L2 [12288,28672) L3 [28672,61440)
__global__ __launch_bounds__(256) void pool_all_kernel(const float* __restrict__ f0,
                                                       const float* __restrict__ f1,
                                                       const float* __restrict__ f2,
                                                       const float* __restrict__ f3,
                                                       float* __restrict__ fq_all) {
    int bid = blockIdx.x;
    int lane = threadIdx.x & 63, w = threadIdx.x >> 6;
    if (bid < 4096) {
        pool_row_vec<3136>(f0, fq_all + 0,      bid * 4 + w, lane);
    } else if (bid < 12288) {
        pool_row_vec<784>(f1, fq_all + 16384,  (bid - 4096) * 4 + w, lane);
    } else if (bid < 28672) {
        pool_row_vec<196>(f2, fq_all + 49152,  (bid - 12288) * 4 + w, lane);
    } else {
        pool_row_49(f3, fq_all + 114688, (bid - 28672) * 4 + w, lane);
    }
}

// ---------------------------------------------------------------- ref norms
__global__ __launch_bounds__(256) void r2_kernel(const float* __restrict__ ref0,
                                                 const float* __restrict__ ref1,
                                                 const float* __restrict__ ref2,
                                                 const float* __restrict__ ref3,
                                                 float* __restrict__ r2_all) {
    int layer = blockIdx.y;
    int w = threadIdx.x >> 6, lane = threadIdx.x & 63;
    int r = blockIdx.x * 4 + w;
    if (r >= NREF) return;
    const float* rp; int C;
    switch (layer) {
        case 0:  rp = ref0; C = 64;  break;
        case 1:  rp = ref1; C = 128; break;
        case 2:  rp = ref2; C = 256; break;
        default: rp = ref3; C = 512; break;
    }
    const float4* row = (const float4*)(rp + (size_t)r * C);
    int n4 = C >> 2;
    float s = 0.f;
    for (int i = lane; i < n4; i += 64) {
        float4 v = row[i];
        s += v.x*v.x + v.y*v.y + v.z*v.z + v.w*v.w;
    }
    #pragma unroll
    for (int off = 32; off; off >>= 1) s += __shfl_down(s, off, 64);
    if (lane == 0) r2_all[layer * NREF + r] = s;
}

// ---------------------------------------------------------------- G = fq @ ref^T  (fused, all layers, split-K)
// fp32 (no fp32 MFMA on CDNA4). 64x64 tile, BK=32, 256 threads, 4x4 acc.
// Flat grid of 1920 blocks: per-layer {128,256,512,1024} = 128 * chunks{1,2,4,8}.
#define BM 64
#define BN 64
#define BK 32
#define LDT 68
__global__ __launch_bounds__(256) void gemm_all(const float* __restrict__ fq_all,
                                                const float* __restrict__ rf0,
                                                const float* __restrict__ rf1,
                                                const float* __restrict__ rf2,
                                                const float* __restrict__ rf3,
                                                float* __restrict__ G_part) {
    __shared__ __align__(16) float As[BK * LDT];
    __shared__ __align__(16) float Bs[BK * LDT];

    int bid = blockIdx.x;
    int layer = (bid >= 128) + (bid >= 384) + (bid >= 896);
    const int offt[4] = {0, 128, 384, 896};
    const int Ks[4]   = {64, 128, 256, 512};
    const int fqo[4]  = {0, 16384, 49152, 114688};
    const int coff[4] = {0, 1, 3, 7};

    int K = Ks[layer];
    const float* A = fq_all + fqo[layer];
    const float* B = layer == 0 ? rf0 : layer == 1 ? rf1 : layer == 2 ? rf2 : rf3;
    int local = bid - offt[layer];
    int chunk = local >> 7;
    int rem   = local & 127;
    int m0 = (rem & 3) * BM;
    int n0 = (rem >> 2) * BN;
    int kb = chunk * KC;
    float* Gout = G_part + (size_t)(coff[layer] + chunk) * G_CHUNK_STRIDE;

    int t = threadIdx.x;
    int tq = t & 15, tr = t >> 4;
    int row0 = t >> 3;
    int kc4  = t & 7;
    float acc[4][4] = {};

    #pragma unroll
    for (int ko = 0; ko < KC / BK; ++ko) {
        int k0 = kb + ko * BK;
        #pragma unroll
        for (int half = 0; half < 2; ++half) {
            int row = row0 + half * 32;
            float4 av = *(const float4*)(A + (size_t)(m0 + row) * K + k0 + kc4 * 4);
            int brow = n0 + row;
            float4 bv = make_float4(0.f, 0.f, 0.f, 0.f);
            if (brow < NREF) bv = *(const float4*)(B + (size_t)brow * K + k0 + kc4 * 4);
            As[(kc4*4 + 0) * LDT + row] = av.x;
            As[(kc4*4 + 1) * LDT + row] = av.y;
            As[(kc4*4 + 2) * LDT + row] = av.z;
            As[(kc4*4 + 3) * LDT + row] = av.w;
            Bs[(kc4*4 + 0) * LDT + row] = bv.x;
            Bs[(kc4*4 + 1) * LDT + row] = bv.y;
            Bs[(kc4*4 + 2) * LDT + row] = bv.z;
            Bs[(kc4*4 + 3) * LDT + row] = bv.w;
        }
        __syncthreads();
        #pragma unroll
        for (int kk = 0; kk < BK; ++kk) {
            float4 a = *(const float4*)&As[kk * LDT + tq * 4];
            float4 b = *(const float4*)&Bs[kk * LDT + tr * 4];
            acc[0][0] += a.x*b.x; acc[0][1] += a.x*b.y; acc[0][2] += a.x*b.z; acc[0][3] += a.x*b.w;
            acc[1][0] += a.y*b.x; acc[1][1] += a.y*b.y; acc[1][2] += a.y*b.z; acc[1][3] += a.y*b.w;
            acc[2][0] += a.z*b.x; acc[2][1] += a.z*b.y; acc[2][2] += a.z*b.z; acc[2][3] += a.z*b.w;
            acc[3][0] += a.w*b.x; acc[3][1] += a.w*b.y; acc[3][2] += a.w*b.z; acc[3][3] += a.w*b.w;
        }
        __syncthreads();
    }

    int rbase = n0 + tr * 4;
    if (rbase < NREF) {   // NREF%4==0 -> float4 group all-valid or all-invalid
        #pragma unroll
        for (int i = 0; i < 4; ++i) {
            float4 o = make_float4(acc[i][0], acc[i][1], acc[i][2], acc[i][3]);
            *(float4*)(Gout + (size_t)(m0 + tq*4 + i) * NREF + rbase) = o;
        }
    }
}

// ---------------------------------------------------------------- top-k + LID via radix histogram
__global__ __launch_bounds__(256) void topk_lid_kernel(const float* __restrict__ fq_all,
                                                       const float* __restrict__ G_all,
                                                       const float* __restrict__ r2_all,
                                                       float* __restrict__ lid,
                                                       const int* __restrict__ kptr) {
    __shared__ __align__(16) float d2s[NREF];
    __shared__ unsigned hist[2048];          // reused as candidate buffer later
    __shared__ float redq[4], redm[4], redl[4];
    __shared__ unsigned long long red8[4];
    __shared__ int sh_B, sh_cbelow, sh_cnt;
    __shared__ float sh_dmin;

    const int Cs[4]   = {64, 128, 256, 512};
    const int fqo[4]  = {0, 16384, 49152, 114688};
    const int nchs[4] = {1, 2, 4, 8};
    const int coff[4] = {0, 1, 3, 7};

    int b = blockIdx.x, layer = blockIdx.y;
    int t = threadIdx.x;
    int lane = t & 63, w = t >> 6;
    int k = kptr[0];
    if (k + 1 > NREF) k = NREF - 1;
    unsigned K1 = (unsigned)(k + 1);
    int C = Cs[layer];
    int nch = nchs[layer];
    const float* fq = fq_all + fqo[layer] + (size_t)b * C;
    const float* Gb = G_all + (size_t)coff[layer] * G_CHUNK_STRIDE + (size_t)b * NREF;
    const float* r2 = r2_all + layer * NREF;
    const float INF = __uint_as_float(0x7f800000u);

    for (int i = t; i < 2048; i += 256) hist[i] = 0u;
    if (t == 0) sh_cnt = 0;
    float s = 0.f;
    for (int c = t; c < C; c += 256) { float v = fq[c]; s += v * v; }
    #pragma unroll
    for (int off = 32; off; off >>= 1) s += __shfl_down(s, off, 64);
    if (lane == 0) redq[w] = s;
    __syncthreads();                                   // B1
    float q2 = redq[0] + redq[1] + redq[2] + redq[3];

    float minv = INF;
    for (int i = t; i < NREF / 4; i += 256) {
        float4 g = make_float4(0.f, 0.f, 0.f, 0.f);
        for (int c = 0; c < nch; ++c) {
            float4 v = *(const float4*)(Gb + (size_t)c * G_CHUNK_STRIDE + i * 4);
            g.x += v.x; g.y += v.y; g.z += v.z; g.w += v.w;
        }
        float4 rr = *(const float4*)(r2 + i * 4);
        float d0 = q2 - 2.f * g.x + rr.x; d0 = d0 > 0.f ? d0 : 0.f;
        float d1 = q2 - 2.f * g.y + rr.y; d1 = d1 > 0.f ? d1 : 0.f;
        float d2_ = q2 - 2.f * g.z + rr.z; d2_ = d2_ > 0.f ? d2_ : 0.f;
        float d3 = q2 - 2.f * g.w + rr.w; d3 = d3 > 0.f ? d3 : 0.f;
        *(float4*)(d2s + i * 4) = make_float4(d0, d1, d2_, d3);
        atomicAdd(&hist[__float_as_uint(d0) >> 20], 1u);
        atomicAdd(&hist[__float_as_uint(d1) >> 20], 1u);
        atomicAdd(&hist[__float_as_uint(d2_) >> 20], 1u);
        atomicAdd(&hist[__float_as_uint(d3) >> 20], 1u);
        minv = fminf(minv, fminf(fminf(d0, d1), fminf(d2_, d3)));
    }
    #pragma unroll
    for (int off = 32; off; off >>= 1) minv = fminf(minv, __shfl_down(minv, off, 64));
    if (lane == 0) redm[w] = minv;
    __syncthreads();                                   // B2

    if (t < 64) {
        unsigned p = 0;
        int base = t * 32;
        #pragma unroll 4
        for (int i = 0; i < 32; ++i) p += hist[base + i];
        unsigned cum = p;
        #pragma unroll
        for (int off = 1; off < 64; off <<= 1) {
            unsigned o = __shfl_up(cum, off, 64);
            if (t >= off) cum += o;
        }
        unsigned excl = cum - p;
        if (excl < K1 && K1 <= cum) {
            unsigned run = excl;
            int binB = base;
            for (int i = 0; i < 32; ++i) {
                unsigned c = hist[base + i];
                if (run + c >= K1) { binB = base + i; break; }
                run += c;
            }
            sh_B = binB;
            sh_cbelow = (int)run;
        }
        if (t == 0) sh_dmin = fminf(fminf(redm[0], redm[1]), fminf(redm[2], redm[3]));
    }
    __syncthreads();                                   // B3

    int B = sh_B;
    float* cand = (float*)hist;
    float lsum = 0.f;
    for (int i = t; i < NREF; i += 256) {
        float v = d2s[i];
        int bin = (int)(__float_as_uint(v) >> 20);
        if (bin < B) {
            lsum += logf(v);
        } else if (bin == B) {
            int pos = atomicAdd(&sh_cnt, 1);
            cand[pos] = v;
        }
    }
    #pragma unroll
    for (int off = 32; off; off >>= 1) lsum += __shfl_down(lsum, off, 64);
    if (lane == 0) redl[w] = lsum;
    __syncthreads();                                   // B4

    int cnt = sh_cnt;
    int m = (int)K1 - sh_cbelow;
    if (cnt <= 64) {
        if (t < 64) {
            float mv = (t < cnt) ? cand[t] : INF;
            float csum = 0.f, dk = 0.f;
            for (int it = 0; it < m; ++it) {
                float x = mv;
                #pragma unroll
                for (int off = 32; off; off >>= 1) x = fminf(x, __shfl_xor(x, off, 64));
                csum += logf(x);
                dk = x;
                unsigned long long ball = __ballot(mv == x);
                int src = __ffsll(ball) - 1;
                if (t == src) mv = INF;
            }
            if (t == 0) {
                float lsum_tot = redl[0] + redl[1] + redl[2] + redl[3];
                float denom = 0.5f * (lsum_tot + csum - logf(sh_dmin) - (float)k * logf(dk));
                lid[b * 4 + layer] = -(float)k / denom;
            }
        }
    } else {
        float csum = 0.f, dk = 0.f;
        for (int it = 0; it < m; ++it) {
            unsigned long long best = ~0ull;
            for (int i = t; i < cnt; i += 256) {
                unsigned long long key =
                    ((unsigned long long)__float_as_uint(cand[i]) << 32) | (unsigned)i;
                if (key < best) best = key;
            }
            #pragma unroll
            for (int off = 32; off; off >>= 1) {
                unsigned long long o = __shfl_down(best, off, 64);
                if (o < best) best = o;
            }
            if (lane == 0) red8[w] = best;
            __syncthreads();
            unsigned long long mm = red8[0];
            #pragma unroll
            for (int ww = 1; ww < 4; ++ww) if (red8[ww] < mm) mm = red8[ww];
            float v = __uint_as_float((unsigned)(mm >> 32));
            if (t == 0) {
                csum += logf(v);
                dk = v;
                cand[(int)(mm & 0xffffffffu)] = INF;
            }
            __syncthreads();
            if (lane == 0 && w == 0) { }   // keep structure
            csum = __shfl(csum, 0, 64);    // no-op for non-t0 correctness (csum only used by t0)
            dk = __shfl(dk, 0, 64);
        }
        if (t == 0) {
            float lsum_tot = redl[0] + redl[1] + redl[2] + redl[3];
            float denom = 0.5f * (lsum_tot + csum - logf(sh_dmin) - (float)k * logf(dk));
            lid[b * 4 + layer] = -(float)k / denom;
        }
    }
}

// ---------------------------------------------------------------- head
__global__ __launch_bounds__(256) void head_kernel(const float* __restrict__ lid,
                                                   const float* __restrict__ w,
                                                   const float* __restrict__ bias,
                                                   float* __restrict__ out) {
    int b = threadIdx.x;
    float acc = bias[0];
    #pragma unroll
    for (int l = 0; l < 4; ++l) acc += lid[b * 4 + l] * w[l];
    out[b] = 1.f / (1.f + expf(-acc));
}

extern "C" void kernel_launch(void* const* d_in, const int* in_sizes, int n_in,
                              void* d_out, int out_size, void* d_ws, size_t ws_size,
                              hipStream_t stream) {
    // dict order: feat0, ref0, feat1, ref1, feat2, ref2, feat3, ref3, reg_w, reg_b, k
    const float* feat[4] = {(const float*)d_in[0], (const float*)d_in[2],
                            (const float*)d_in[4], (const float*)d_in[6]};
    const float* ref[4]  = {(const float*)d_in[1], (const float*)d_in[3],
                            (const float*)d_in[5], (const float*)d_in[7]};
    const float* reg_w = (const float*)d_in[8];
    const float* reg_b = (const float*)d_in[9];
    const int*   kptr  = (const int*)d_in[10];

    float* ws     = (float*)d_ws;
    float* fq_all = ws + WS_FQ_OFF;
    float* r2_all = ws + WS_R2_OFF;
    float* lid    = ws + WS_LID_OFF;
    float* G_part = ws + WS_G_OFF;

    pool_all_kernel<<<61440, 256, 0, stream>>>(feat[0], feat[1], feat[2], feat[3], fq_all);
    r2_kernel<<<dim3(NREF / 4, 4), 256, 0, stream>>>(ref[0], ref[1], ref[2], ref[3], r2_all);
    gemm_all<<<1920, 256, 0, stream>>>(fq_all, ref[0], ref[1], ref[2], ref[3], G_part);
    topk_lid_kernel<<<dim3(256, 4), 256, 0, stream>>>(fq_all, G_part, r2_all, lid, kptr);
    head_kernel<<<1, 256, 0, stream>>>(lid, reg_w, reg_b, (float*)d_out);
}

// Round 4
// 487.982 us; speedup vs baseline: 1.0038x; 1.0038x over previous
//
#include <hip/hip_runtime.h>
#include <cmath>

// Workspace layout (in floats):
//   fq_all : 0       .. 245760   (256 x (64+128+256+512))
//   r2_all : 245760  .. 253760   (4 x 2000)
//   lid    : 253760  .. 254784   (256 x 4, [b][layer])
//   G_part : 262144  ..          (15 chunks x 256 x 2000)  ~31 MB total
#define WS_FQ_OFF      0u
#define WS_R2_OFF      245760u
#define WS_LID_OFF     253760u
#define WS_G_OFF       262144u
#define G_CHUNK_STRIDE 512000u
#define NREF           2000
#define KC             64       // split-K chunk width

// ---------------------------------------------------------------- pooling (fused, all layers)
// Latency-oriented design: each wave owns 2 rows (layer0) or 4 rows (layers 1-3)
// with independent accumulators -> >=4 vmem ops in flight per wave at all times.
// Main-body loads are UNconditional; only genuine tails are predicated.

__device__ __forceinline__ float wave_sum(float s) {
    #pragma unroll
    for (int off = 32; off; off >>= 1) s += __shfl_down(s, off, 64);
    return s;
}

// layer0: HW=3136, N4=784 = 12*64 + 16. Two rows per wave.
__device__ __forceinline__ void pool2_3136(const float* __restrict__ feat,
                                           float* __restrict__ fq,
                                           int row0, int lane) {
    const float4* a = (const float4*)(feat + (size_t)row0 * 3136);
    const float4* b = (const float4*)(feat + (size_t)(row0 + 1) * 3136);
    float s0 = 0.f, s1 = 0.f;
    #pragma unroll
    for (int it = 0; it < 12; ++it) {
        float4 x = a[lane + it * 64];
        float4 y = b[lane + it * 64];
        s0 += (x.x + x.y) + (x.z + x.w);
        s1 += (y.x + y.y) + (y.z + y.w);
    }
    if (lane < 16) {
        float4 x = a[768 + lane];
        float4 y = b[768 + lane];
        s0 += (x.x + x.y) + (x.z + x.w);
        s1 += (y.x + y.y) + (y.z + y.w);
    }
    s0 = wave_sum(s0);
    s1 = wave_sum(s1);
    if (lane == 0) *(float2*)(fq + row0) = make_float2(s0 * (1.f/3136.f), s1 * (1.f/3136.f));
}

// layer1: HW=784, N4=196 = 3*64 + 4. Four rows per wave.
__device__ __forceinline__ void pool4_784(const float* __restrict__ feat,
                                          float* __restrict__ fq,
                                          int row0, int lane) {
    float s[4] = {0.f, 0.f, 0.f, 0.f};
    const float4* p[4];
    #pragma unroll
    for (int r = 0; r < 4; ++r) p[r] = (const float4*)(feat + (size_t)(row0 + r) * 784);
    #pragma unroll
    for (int it = 0; it < 3; ++it) {
        #pragma unroll
        for (int r = 0; r < 4; ++r) {
            float4 v = p[r][lane + it * 64];
            s[r] += (v.x + v.y) + (v.z + v.w);
        }
    }
    if (lane < 4) {
        #pragma unroll
        for (int r = 0; r < 4; ++r) {
            float4 v = p[r][192 + lane];
            s[r] += (v.x + v.y) + (v.z + v.w);
        }
    }
    #pragma unroll
    for (int r = 0; r < 4; ++r) s[r] = wave_sum(s[r]);
    if (lane == 0)
        *(float4*)(fq + row0) = make_float4(s[0]*(1.f/784.f), s[1]*(1.f/784.f),
                                            s[2]*(1.f/784.f), s[3]*(1.f/784.f));
}

// layer2: HW=196, N4=49. Four rows per wave, one predicated float4 load each.
__device__ __forceinline__ void pool4_196(const float* __restrict__ feat,
                                          float* __restrict__ fq,
                                          int row0, int lane) {
    float s[4];
    #pragma unroll
    for (int r = 0; r < 4; ++r) {
        const float4* p = (const float4*)(feat + (size_t)(row0 + r) * 196);
        float4 v = (lane < 49) ? p[lane] : make_float4(0.f, 0.f, 0.f, 0.f);
        s[r] = (v.x + v.y) + (v.z + v.w);
    }
    #pragma unroll
    for (int r = 0; r < 4; ++r) s[r] = wave_sum(s[r]);
    if (lane == 0)
        *(float4*)(fq + row0) = make_float4(s[0]*(1.f/196.f), s[1]*(1.f/196.f),
                                            s[2]*(1.f/196.f), s[3]*(1.f/196.f));
}

// layer3: HW=49 (odd). Four rows per wave, one predicated scalar load each.
__device__ __forceinline__ void pool4_49(const float* __restrict__ feat,
                                         float* __restrict__ fq,
                                         int row0, int lane) {
    float s[4];
    #pragma unroll
    for (int r = 0; r < 4; ++r) {
        const float* p = feat + (size_t)(row0 + r) * 49;
        s[r] = (lane < 49) ? p[lane] : 0.f;
    }
    #pragma unroll
    for (int r = 0; r < 4; ++r) s[r] = wave_sum(s[r]);
    if (lane == 0)
        *(float4*)(fq + row0) = make_float4(s[0]*(1.f/49.f), s[1]*(1.f/49.f),
                                            s[2]*(1.f/49.f), s[3]*(1.f/49.f));
}

// Block ranges: L0 [0,2048) 8 rows/blk · L1 [2048,4096) 16 rows/blk
//               L2 [4096,8192) 16 rows/blk · L3 [8192,16384) 16 rows/blk
__global__ __launch_bounds__(256) void pool_all_kernel(const float* __restrict__ f0,
                                                       const float* __restrict__ f1,
                                                       const float* __restrict__ f2,
                                                       const float* __restrict__ f3,
                                                       float* __restrict__ fq_all) {
    int bid = blockIdx.x;
    int lane = threadIdx.x & 63, w = threadIdx.x >> 6;
    if (bid < 2048) {
        pool2_3136(f0, fq_all + 0,      bid * 8 + w * 2, lane);
    } else if (bid < 4096) {
        pool4_784(f1, fq_all + 16384,  (bid - 2048) * 16 + w * 4, lane);
    } else if (bid < 8192) {
        pool4_196(f2, fq_all + 49152,  (bid - 4096) * 16 + w * 4, lane);
    } else {
        pool4_49(f3, fq_all + 114688, (bid - 8192) * 16 + w * 4, lane);
    }
}

// ---------------------------------------------------------------- ref norms
__global__ __launch_bounds__(256) void r2_kernel(const float* __restrict__ ref0,
                                                 const float* __restrict__ ref1,
                                                 const float* __restrict__ ref2,
                                                 const float* __restrict__ ref3,
                                                 float* __restrict__ r2_all) {
    int layer = blockIdx.y;
    int w = threadIdx.x >> 6, lane = threadIdx.x & 63;
    int r = blockIdx.x * 4 + w;
    if (r >= NREF) return;
    const float* rp; int C;
    switch (layer) {
        case 0:  rp = ref0; C = 64;  break;
        case 1:  rp = ref1; C = 128; break;
        case 2:  rp = ref2; C = 256; break;
        default: rp = ref3; C = 512; break;
    }
    const float4* row = (const float4*)(rp + (size_t)r * C);
    int n4 = C >> 2;
    float s = 0.f;
    for (int i = lane; i < n4; i += 64) {
        float4 v = row[i];
        s += v.x*v.x + v.y*v.y + v.z*v.z + v.w*v.w;
    }
    s = wave_sum(s);
    if (lane == 0) r2_all[layer * NREF + r] = s;
}

// ---------------------------------------------------------------- G = fq @ ref^T  (fused, all layers, split-K)
#define BM 64
#define BN 64
#define BK 32
#define LDT 68
__global__ __launch_bounds__(256) void gemm_all(const float* __restrict__ fq_all,
                                                const float* __restrict__ rf0,
                                                const float* __restrict__ rf1,
                                                const float* __restrict__ rf2,
                                                const float* __restrict__ rf3,
                                                float* __restrict__ G_part) {
    __shared__ __align__(16) float As[BK * LDT];
    __shared__ __align__(16) float Bs[BK * LDT];

    int bid = blockIdx.x;
    int layer = (bid >= 128) + (bid >= 384) + (bid >= 896);
    const int offt[4] = {0, 128, 384, 896};
    const int Ks[4]   = {64, 128, 256, 512};
    const int fqo[4]  = {0, 16384, 49152, 114688};
    const int coff[4] = {0, 1, 3, 7};

    int K = Ks[layer];
    const float* A = fq_all + fqo[layer];
    const float* B = layer == 0 ? rf0 : layer == 1 ? rf1 : layer == 2 ? rf2 : rf3;
    int local = bid - offt[layer];
    int chunk = local >> 7;
    int rem   = local & 127;
    int m0 = (rem & 3) * BM;
    int n0 = (rem >> 2) * BN;
    int kb = chunk * KC;
    float* Gout = G_part + (size_t)(coff[layer] + chunk) * G_CHUNK_STRIDE;

    int t = threadIdx.x;
    int tq = t & 15, tr = t >> 4;
    int row0 = t >> 3;
    int kc4  = t & 7;
    float acc[4][4] = {};

    #pragma unroll
    for (int ko = 0; ko < KC / BK; ++ko) {
        int k0 = kb + ko * BK;
        #pragma unroll
        for (int half = 0; half < 2; ++half) {
            int row = row0 + half * 32;
            float4 av = *(const float4*)(A + (size_t)(m0 + row) * K + k0 + kc4 * 4);
            int brow = n0 + row;
            float4 bv = make_float4(0.f, 0.f, 0.f, 0.f);
            if (brow < NREF) bv = *(const float4*)(B + (size_t)brow * K + k0 + kc4 * 4);
            As[(kc4*4 + 0) * LDT + row] = av.x;
            As[(kc4*4 + 1) * LDT + row] = av.y;
            As[(kc4*4 + 2) * LDT + row] = av.z;
            As[(kc4*4 + 3) * LDT + row] = av.w;
            Bs[(kc4*4 + 0) * LDT + row] = bv.x;
            Bs[(kc4*4 + 1) * LDT + row] = bv.y;
            Bs[(kc4*4 + 2) * LDT + row] = bv.z;
            Bs[(kc4*4 + 3) * LDT + row] = bv.w;
        }
        __syncthreads();
        #pragma unroll
        for (int kk = 0; kk < BK; ++kk) {
            float4 a = *(const float4*)&As[kk * LDT + tq * 4];
            float4 b = *(const float4*)&Bs[kk * LDT + tr * 4];
            acc[0][0] += a.x*b.x; acc[0][1] += a.x*b.y; acc[0][2] += a.x*b.z; acc[0][3] += a.x*b.w;
            acc[1][0] += a.y*b.x; acc[1][1] += a.y*b.y; acc[1][2] += a.y*b.z; acc[1][3] += a.y*b.w;
            acc[2][0] += a.z*b.x; acc[2][1] += a.z*b.y; acc[2][2] += a.z*b.z; acc[2][3] += a.z*b.w;
            acc[3][0] += a.w*b.x; acc[3][1] += a.w*b.y; acc[3][2] += a.w*b.z; acc[3][3] += a.w*b.w;
        }
        __syncthreads();
    }

    int rbase = n0 + tr * 4;
    if (rbase < NREF) {
        #pragma unroll
        for (int i = 0; i < 4; ++i) {
            float4 o = make_float4(acc[i][0], acc[i][1], acc[i][2], acc[i][3]);
            *(float4*)(Gout + (size_t)(m0 + tq*4 + i) * NREF + rbase) = o;
        }
    }
}

// ---------------------------------------------------------------- top-k + LID via radix histogram
__global__ __launch_bounds__(256) void topk_lid_kernel(const float* __restrict__ fq_all,
                                                       const float* __restrict__ G_all,
                                                       const float* __restrict__ r2_all,
                                                       float* __restrict__ lid,
                                                       const int* __restrict__ kptr) {
    __shared__ __align__(16) float d2s[NREF];
    __shared__ unsigned hist[2048];          // reused as candidate buffer later
    __shared__ float redq[4], redm[4], redl[4];
    __shared__ unsigned long long red8[4];
    __shared__ int sh_B, sh_cbelow, sh_cnt;
    __shared__ float sh_dmin;

    const int Cs[4]   = {64, 128, 256, 512};
    const int fqo[4]  = {0, 16384, 49152, 114688};
    const int nchs[4] = {1, 2, 4, 8};
    const int coff[4] = {0, 1, 3, 7};

    int b = blockIdx.x, layer = blockIdx.y;
    int t = threadIdx.x;
    int lane = t & 63, w = t >> 6;
    int k = kptr[0];
    if (k + 1 > NREF) k = NREF - 1;
    unsigned K1 = (unsigned)(k + 1);
    int C = Cs[layer];
    int nch = nchs[layer];
    const float* fq = fq_all + fqo[layer] + (size_t)b * C;
    const float* Gb = G_all + (size_t)coff[layer] * G_CHUNK_STRIDE + (size_t)b * NREF;
    const float* r2 = r2_all + layer * NREF;
    const float INF = __uint_as_float(0x7f800000u);

    for (int i = t; i < 2048; i += 256) hist[i] = 0u;
    if (t == 0) sh_cnt = 0;
    float s = 0.f;
    for (int c = t; c < C; c += 256) { float v = fq[c]; s += v * v; }
    s = wave_sum(s);
    if (lane == 0) redq[w] = s;
    __syncthreads();                                   // B1
    float q2 = redq[0] + redq[1] + redq[2] + redq[3];

    float minv = INF;
    for (int i = t; i < NREF / 4; i += 256) {
        float4 g = make_float4(0.f, 0.f, 0.f, 0.f);
        for (int c = 0; c < nch; ++c) {
            float4 v = *(const float4*)(Gb + (size_t)c * G_CHUNK_STRIDE + i * 4);
            g.x += v.x; g.y += v.y; g.z += v.z; g.w += v.w;
        }
        float4 rr = *(const float4*)(r2 + i * 4);
        float d0 = q2 - 2.f * g.x + rr.x; d0 = d0 > 0.f ? d0 : 0.f;
        float d1 = q2 - 2.f * g.y + rr.y; d1 = d1 > 0.f ? d1 : 0.f;
        float d2_ = q2 - 2.f * g.z + rr.z; d2_ = d2_ > 0.f ? d2_ : 0.f;
        float d3 = q2 - 2.f * g.w + rr.w; d3 = d3 > 0.f ? d3 : 0.f;
        *(float4*)(d2s + i * 4) = make_float4(d0, d1, d2_, d3);
        atomicAdd(&hist[__float_as_uint(d0) >> 20], 1u);
        atomicAdd(&hist[__float_as_uint(d1) >> 20], 1u);
        atomicAdd(&hist[__float_as_uint(d2_) >> 20], 1u);
        atomicAdd(&hist[__float_as_uint(d3) >> 20], 1u);
        minv = fminf(minv, fminf(fminf(d0, d1), fminf(d2_, d3)));
    }
    #pragma unroll
    for (int off = 32; off; off >>= 1) minv = fminf(minv, __shfl_down(minv, off, 64));
    if (lane == 0) redm[w] = minv;
    __syncthreads();                                   // B2

    if (t < 64) {
        unsigned p = 0;
        int base = t * 32;
        #pragma unroll 4
        for (int i = 0; i < 32; ++i) p += hist[base + i];
        unsigned cum = p;
        #pragma unroll
        for (int off = 1; off < 64; off <<= 1) {
            unsigned o = __shfl_up(cum, off, 64);
            if (t >= off) cum += o;
        }
        unsigned excl = cum - p;
        if (excl < K1 && K1 <= cum) {
            unsigned run = excl;
            int binB = base;
            for (int i = 0; i < 32; ++i) {
                unsigned c = hist[base + i];
                if (run + c >= K1) { binB = base + i; break; }
                run += c;
            }
            sh_B = binB;
            sh_cbelow = (int)run;
        }
        if (t == 0) sh_dmin = fminf(fminf(redm[0], redm[1]), fminf(redm[2], redm[3]));
    }
    __syncthreads();                                   // B3

    int B = sh_B;
    float* cand = (float*)hist;
    float lsum = 0.f;
    for (int i = t; i < NREF; i += 256) {
        float v = d2s[i];
        int bin = (int)(__float_as_uint(v) >> 20);
        if (bin < B) {
            lsum += logf(v);
        } else if (bin == B) {
            int pos = atomicAdd(&sh_cnt, 1);
            cand[pos] = v;
        }
    }
    lsum = wave_sum(lsum);
    if (lane == 0) redl[w] = lsum;
    __syncthreads();                                   // B4

    int cnt = sh_cnt;
    int m = (int)K1 - sh_cbelow;
    if (cnt <= 64) {
        if (t < 64) {
            float mv = (t < cnt) ? cand[t] : INF;
            float csum = 0.f, dk = 0.f;
            for (int it = 0; it < m; ++it) {
                float x = mv;
                #pragma unroll
                for (int off = 32; off; off >>= 1) x = fminf(x, __shfl_xor(x, off, 64));
                csum += logf(x);
                dk = x;
                unsigned long long ball = __ballot(mv == x);
                int src = __ffsll(ball) - 1;
                if (t == src) mv = INF;
            }
            if (t == 0) {
                float lsum_tot = redl[0] + redl[1] + redl[2] + redl[3];
                float denom = 0.5f * (lsum_tot + csum - logf(sh_dmin) - (float)k * logf(dk));
                lid[b * 4 + layer] = -(float)k / denom;
            }
        }
    } else {
        float csum = 0.f, dk = 0.f;
        for (int it = 0; it < m; ++it) {
            unsigned long long best = ~0ull;
            for (int i = t; i < cnt; i += 256) {
                unsigned long long key =
                    ((unsigned long long)__float_as_uint(cand[i]) << 32) | (unsigned)i;
                if (key < best) best = key;
            }
            #pragma unroll
            for (int off = 32; off; off >>= 1) {
                unsigned long long o = __shfl_down(best, off, 64);
                if (o < best) best = o;
            }
            if (lane == 0) red8[w] = best;
            __syncthreads();
            unsigned long long mm = red8[0];
            #pragma unroll
            for (int ww = 1; ww < 4; ++ww) if (red8[ww] < mm) mm = red8[ww];
            float v = __uint_as_float((unsigned)(mm >> 32));
            csum += logf(v);
            dk = v;
            if (t == 0) cand[(int)(mm & 0xffffffffu)] = INF;
            __syncthreads();
        }
        if (t == 0) {
            float lsum_tot = redl[0] + redl[1] + redl[2] + redl[3];
            float denom = 0.5f * (lsum_tot + csum - logf(sh_dmin) - (float)k * logf(dk));
            lid[b * 4 + layer] = -(float)k / denom;
        }
    }
}

// ---------------------------------------------------------------- head
__global__ __launch_bounds__(256) void head_kernel(const float* __restrict__ lid,
                                                   const float* __restrict__ w,
                                                   const float* __restrict__ bias,
                                                   float* __restrict__ out) {
    int b = threadIdx.x;
    float acc = bias[0];
    #pragma unroll
    for (int l = 0; l < 4; ++l) acc += lid[b * 4 + l] * w[l];
    out[b] = 1.f / (1.f + expf(-acc));
}

extern "C" void kernel_launch(void* const* d_in, const int* in_sizes, int n_in,
                              void* d_out, int out_size, void* d_ws, size_t ws_size,
                              hipStream_t stream) {
    // dict order: feat0, ref0, feat1, ref1, feat2, ref2, feat3, ref3, reg_w, reg_b, k
    const float* feat[4] = {(const float*)d_in[0], (const float*)d_in[2],
                            (const float*)d_in[4], (const float*)d_in[6]};
    const float* ref[4]  = {(const float*)d_in[1], (const float*)d_in[3],
                            (const float*)d_in[5], (const float*)d_in[7]};
    const float* reg_w = (const float*)d_in[8];
    const float* reg_b = (const float*)d_in[9];
    const int*   kptr  = (const int*)d_in[10];

    float* ws     = (float*)d_ws;
    float* fq_all = ws + WS_FQ_OFF;
    float* r2_all = ws + WS_R2_OFF;
    float* lid    = ws + WS_LID_OFF;
    float* G_part = ws + WS_G_OFF;

    pool_all_kernel<<<16384, 256, 0, stream>>>(feat[0], feat[1], feat[2], feat[3], fq_all);
    r2_kernel<<<dim3(NREF / 4, 4), 256, 0, stream>>>(ref[0], ref[1], ref[2], ref[3], r2_all);
    gemm_all<<<1920, 256, 0, stream>>>(fq_all, ref[0], ref[1], ref[2], ref[3], G_part);
    topk_lid_kernel<<<dim3(256, 4), 256, 0, stream>>>(fq_all, G_part, r2_all, lid, kptr);
    head_kernel<<<1, 256, 0, stream>>>(lid, reg_w, reg_b, (float*)d_out);
}